// Round 1
// 5322.153 us; speedup vs baseline: 3.3191x; 3.3191x over previous
//
#include <hip/hip_runtime.h>
#include <math.h>

#define NB 4
#define SEQ 1024
#define DIM 768
#define NH 12
#define HD 64
#define FF 3072
#define NL 12
#define VOCAB 50257
#define NTOK 4096   // NB*SEQ

typedef unsigned short u16;
typedef __attribute__((ext_vector_type(8))) short short8;   // 8 bf16 (guide-verified frag type)
typedef __attribute__((ext_vector_type(4))) float floatx4;

__device__ __forceinline__ u16 f2bf(float f) {
  union { float f; unsigned u; } v; v.f = f;
  unsigned u = v.u;
  u += 0x7fffu + ((u >> 16) & 1u);   // RNE
  return (u16)(u >> 16);
}

// ---------------- embedding: x[row] = tok[id] + pos[s] ----------------
__global__ __launch_bounds__(256) void embed_kernel(const int* __restrict__ ids,
                                                    const float* __restrict__ tok,
                                                    const float* __restrict__ pos,
                                                    float* __restrict__ x) {
  int row = blockIdx.x;
  int s = row & (SEQ - 1);
  int id = ids[row];
  const float* te = tok + (size_t)id * DIM;
  const float* pe = pos + (size_t)s * DIM;
  float* xr = x + (size_t)row * DIM;
  for (int d = threadIdx.x; d < DIM; d += 256) xr[d] = te[d] + pe[d];
}

// ---------------- layernorm: fp32 in -> bf16 out ----------------
__global__ __launch_bounds__(256) void ln_kernel(const float* __restrict__ x,
                                                 const float* __restrict__ g,
                                                 const float* __restrict__ b,
                                                 u16* __restrict__ out) {
  int row = blockIdx.x;
  const float* xr = x + (size_t)row * DIM;
  int t = threadIdx.x;
  float v0 = xr[t], v1 = xr[t + 256], v2 = xr[t + 512];
  float s = v0 + v1 + v2;
  float s2 = v0*v0 + v1*v1 + v2*v2;
  #pragma unroll
  for (int off = 32; off; off >>= 1) { s += __shfl_xor(s, off); s2 += __shfl_xor(s2, off); }
  __shared__ float rs[4], rs2[4];
  int wave = t >> 6;
  if ((t & 63) == 0) { rs[wave] = s; rs2[wave] = s2; }
  __syncthreads();
  s = rs[0] + rs[1] + rs[2] + rs[3];
  s2 = rs2[0] + rs2[1] + rs2[2] + rs2[3];
  float mean = s * (1.f / DIM);
  float var = s2 * (1.f / DIM) - mean * mean;
  float rstd = rsqrtf(var + 1e-5f);
  u16* orow = out + (size_t)row * DIM;
  orow[t]       = f2bf(g[t]       * ((v0 - mean) * rstd) + b[t]);
  orow[t + 256] = f2bf(g[t + 256] * ((v1 - mean) * rstd) + b[t + 256]);
  orow[t + 512] = f2bf(g[t + 512] * ((v2 - mean) * rstd) + b[t + 512]);
}

// ---------------- weight prep: fp32 [K,N] -> bf16 [N,K], batched over layers ----------------
__global__ __launch_bounds__(256) void transpose_cast_kernel(const float* __restrict__ in,
                                                             u16* __restrict__ out, int K, int N) {
  __shared__ float tile[64][65];
  size_t off = (size_t)blockIdx.z * K * N;
  in += off; out += off;
  int k0 = blockIdx.y * 64, n0 = blockIdx.x * 64;
  int t = threadIdx.x;
  #pragma unroll
  for (int i = 0; i < 4; i++) {
    int idx = t + 256 * i;
    int r = idx >> 4, c = (idx & 15) * 4;
    float4 v = *(const float4*)&in[(size_t)(k0 + r) * N + n0 + c];
    tile[r][c] = v.x; tile[r][c+1] = v.y; tile[r][c+2] = v.z; tile[r][c+3] = v.w;
  }
  __syncthreads();
  #pragma unroll
  for (int i = 0; i < 4; i++) {
    int idx = t + 256 * i;
    int rn = idx >> 4, ck = (idx & 15) * 4;
    ushort4 o;
    o.x = f2bf(tile[ck+0][rn]); o.y = f2bf(tile[ck+1][rn]);
    o.z = f2bf(tile[ck+2][rn]); o.w = f2bf(tile[ck+3][rn]);
    *(ushort4*)&out[(size_t)(n0 + rn) * K + k0 + ck] = o;
  }
}

// ---------------- plain fp32 -> bf16 cast (tok_embed for lm_head) ----------------
__global__ __launch_bounds__(256) void cast_bf16_kernel(const float* __restrict__ in,
                                                        u16* __restrict__ out, long n4) {
  long i = (long)blockIdx.x * 256 + threadIdx.x;
  if (i >= n4) return;
  float4 v = ((const float4*)in)[i];
  ushort4 o; o.x = f2bf(v.x); o.y = f2bf(v.y); o.z = f2bf(v.z); o.w = f2bf(v.w);
  ((ushort4*)out)[i] = o;
}

// ---------------- GEMM: C[M,N] = A[M,K](bf16) * Bt[N,K](bf16)^T + epilogue ----------------
// EPI: 0=none, 1=+bias, 2=+bias+resid, 3=+bias+gelu.  OUTBF: bf16 out if 1 else fp32.
template<int EPI, int OUTBF>
__global__ __launch_bounds__(256) void gemm_bt(const u16* __restrict__ A,
                                               const u16* __restrict__ Bt,
                                               const float* __restrict__ bias,
                                               const float* __restrict__ resid,
                                               float* __restrict__ outF,
                                               u16* __restrict__ outB,
                                               int M, int N, int K) {
  __shared__ u16 As[128 * 40];
  __shared__ u16 Bs[128 * 40];
  const int t = threadIdx.x;
  const int m0 = blockIdx.y * 128, n0 = blockIdx.x * 128;
  const int lane = t & 63, wave = t >> 6;
  const int wm = (wave >> 1) * 64, wn = (wave & 1) * 64;
  const int l15 = lane & 15, quad = lane >> 4;

  floatx4 acc[4][4];
  #pragma unroll
  for (int i = 0; i < 4; i++)
    #pragma unroll
    for (int j = 0; j < 4; j++) { floatx4 z = {0.f, 0.f, 0.f, 0.f}; acc[i][j] = z; }

  for (int k0 = 0; k0 < K; k0 += 32) {
    #pragma unroll
    for (int i = 0; i < 2; i++) {
      int idx = t + 256 * i;
      int row = idx >> 2, c8 = (idx & 3) << 3;
      *(uint4*)&As[row * 40 + c8] = *(const uint4*)&A[(size_t)(m0 + row) * K + k0 + c8];
      int nr = n0 + row;
      uint4 bv = {0u, 0u, 0u, 0u};
      if (nr < N) bv = *(const uint4*)&Bt[(size_t)nr * K + k0 + c8];
      *(uint4*)&Bs[row * 40 + c8] = bv;
    }
    __syncthreads();
    short8 af[4], bfr[4];
    #pragma unroll
    for (int mi = 0; mi < 4; mi++) af[mi] = *(const short8*)&As[(wm + mi * 16 + l15) * 40 + quad * 8];
    #pragma unroll
    for (int ni = 0; ni < 4; ni++) bfr[ni] = *(const short8*)&Bs[(wn + ni * 16 + l15) * 40 + quad * 8];
    #pragma unroll
    for (int mi = 0; mi < 4; mi++)
      #pragma unroll
      for (int ni = 0; ni < 4; ni++)
        acc[mi][ni] = __builtin_amdgcn_mfma_f32_16x16x32_bf16(af[mi], bfr[ni], acc[mi][ni], 0, 0, 0);
    __syncthreads();
  }

  #pragma unroll
  for (int mi = 0; mi < 4; mi++) {
    #pragma unroll
    for (int ni = 0; ni < 4; ni++) {
      int gc = n0 + wn + ni * 16 + l15;
      if (gc >= N) continue;
      #pragma unroll
      for (int r = 0; r < 4; r++) {
        int gr = m0 + wm + mi * 16 + quad * 4 + r;
        float v = acc[mi][ni][r];
        if (EPI >= 1) v += bias[gc];
        if (EPI == 2) v += resid[(size_t)gr * N + gc];
        if (EPI == 3) {
          float u = 0.7978845608028654f * (v + 0.044715f * v * v * v);
          v = 0.5f * v * (1.f + tanhf(u));
        }
        size_t o = (size_t)gr * N + gc;
        if (OUTBF) outB[o] = f2bf(v); else outF[o] = v;
      }
    }
  }
}

// ---------------- MFMA flash attention: qkv bf16 [NTOK, 3*DIM] -> out bf16 [NTOK, DIM] ----------
// Block: one (b,h), 64 q-rows. 4 waves, wave w owns q-rows [w*16, w*16+16).
// LDS tiles use the GEMM-proven two-slab layout: offset = (col>>5)*2560 + row*40 + (col&31).
// QPs holds Q during init (frags hoisted to regs), then is reused as the P tile.
__global__ __launch_bounds__(256) void attn_mfma_kernel(const u16* __restrict__ qkv,
                                                        u16* __restrict__ out) {
  __shared__ u16 QPs[5120];
  __shared__ u16 Ks[5120];
  __shared__ u16 Vt[5120];
  const int qb = 15 - blockIdx.x;       // longest-first for causal imbalance
  const int bh = blockIdx.y;            // b*NH + h
  const int bb = bh / NH, hh = bh % NH;
  const int rowBase = bb * SEQ;
  const int q0 = qb * 64;
  const int t = threadIdx.x, lane = t & 63, wave = t >> 6;
  const int l15 = lane & 15, quad = lane >> 4;
  const int wm = wave * 16;             // wave's first q-row within tile

  // ---- stage Q tile (bf16 passthrough), hoist A-frags to registers ----
  #pragma unroll
  for (int i = 0; i < 2; i++) {
    int idx = t + 256 * i;
    int r = idx >> 3, c8 = (idx & 7) * 8;
    *(uint4*)&QPs[(c8 >> 5) * 2560 + r * 40 + (c8 & 31)] =
        *(const uint4*)&qkv[(size_t)(rowBase + q0 + r) * 2304 + hh * 64 + c8];
  }
  __syncthreads();
  short8 af_q[2];
  af_q[0] = *(const short8*)&QPs[(wm + l15) * 40 + quad * 8];
  af_q[1] = *(const short8*)&QPs[2560 + (wm + l15) * 40 + quad * 8];

  floatx4 acc_o[4];
  float m_i[4], l_i[4];
  #pragma unroll
  for (int ni = 0; ni < 4; ni++) { floatx4 z = {0.f, 0.f, 0.f, 0.f}; acc_o[ni] = z; }
  #pragma unroll
  for (int r = 0; r < 4; r++) { m_i[r] = -1e30f; l_i[r] = 0.f; }

  for (int kt = 0; kt <= qb; kt++) {
    __syncthreads();                    // protect Ks/Vt from previous iteration's readers
    // ---- stage K tile ----
    #pragma unroll
    for (int i = 0; i < 2; i++) {
      int idx = t + 256 * i;
      int r = idx >> 3, c8 = (idx & 7) * 8;
      *(uint4*)&Ks[(c8 >> 5) * 2560 + r * 40 + (c8 & 31)] =
          *(const uint4*)&qkv[(size_t)(rowBase + kt * 64 + r) * 2304 + 768 + hh * 64 + c8];
    }
    // ---- stage V tile transposed: Vt[d][kv] = V[kv][d] ----
    #pragma unroll
    for (int i = 0; i < 4; i++) {
      int idx = t + 256 * i;
      int d = idx & 63, kv0 = (idx >> 6) * 4;
      const u16* src = &qkv[(size_t)(rowBase + kt * 64 + kv0) * 2304 + 1536 + hh * 64 + d];
      ushort4 o;
      o.x = src[0]; o.y = src[2304]; o.z = src[2 * 2304]; o.w = src[3 * 2304];
      *(ushort4*)&Vt[(kv0 >> 5) * 2560 + d * 40 + (kv0 & 31)] = o;
    }
    __syncthreads();

    // ---- scores: acc_s[ni] = Q(16 x 64) . K^T, C layout row=quad*4+r col=ni*16+l15 ----
    floatx4 acc_s[4];
    #pragma unroll
    for (int ni = 0; ni < 4; ni++) {
      floatx4 z = {0.f, 0.f, 0.f, 0.f}; acc_s[ni] = z;
      #pragma unroll
      for (int ks = 0; ks < 2; ks++) {
        short8 bk = *(const short8*)&Ks[ks * 2560 + (ni * 16 + l15) * 40 + quad * 8];
        acc_s[ni] = __builtin_amdgcn_mfma_f32_16x16x32_bf16(af_q[ks], bk, acc_s[ni], 0, 0, 0);
      }
    }

    // ---- online softmax (rows are quad-private: 4-step butterfly over 16 lanes) ----
    const bool diag = (kt == qb);
    #pragma unroll
    for (int r = 0; r < 4; r++) {
      float mx = -1e30f;
      #pragma unroll
      for (int ni = 0; ni < 4; ni++) {
        float s = acc_s[ni][r] * 0.125f;
        if (diag && (ni * 16 + l15) > (wm + quad * 4 + r)) s = -1e30f;
        acc_s[ni][r] = s;
        mx = fmaxf(mx, s);
      }
      #pragma unroll
      for (int off = 8; off; off >>= 1) mx = fmaxf(mx, __shfl_xor(mx, off));
      float mnew = fmaxf(m_i[r], mx);
      float alpha = __expf(m_i[r] - mnew);
      m_i[r] = mnew;
      float rs = 0.f;
      #pragma unroll
      for (int ni = 0; ni < 4; ni++) {
        float pv = __expf(acc_s[ni][r] - mnew);
        acc_s[ni][r] = pv;
        rs += pv;
      }
      #pragma unroll
      for (int off = 8; off; off >>= 1) rs += __shfl_xor(rs, off);
      l_i[r] = l_i[r] * alpha + rs;
      #pragma unroll
      for (int ni = 0; ni < 4; ni++) acc_o[ni][r] *= alpha;
      // write P row to LDS (wave-private rows wm..wm+15)
      int row = wm + quad * 4 + r;
      #pragma unroll
      for (int ni = 0; ni < 4; ni++) {
        int col = ni * 16 + l15;
        QPs[(col >> 5) * 2560 + row * 40 + (col & 31)] = f2bf(acc_s[ni][r]);
      }
    }
    asm volatile("s_waitcnt lgkmcnt(0)" ::: "memory");  // wave-private P write->read fence

    // ---- O += P(16 x 64) . V : A-frags from QPs, B-frags from Vt ----
    short8 pa[2];
    pa[0] = *(const short8*)&QPs[(wm + l15) * 40 + quad * 8];
    pa[1] = *(const short8*)&QPs[2560 + (wm + l15) * 40 + quad * 8];
    #pragma unroll
    for (int ni = 0; ni < 4; ni++) {
      #pragma unroll
      for (int ks = 0; ks < 2; ks++) {
        short8 bv = *(const short8*)&Vt[ks * 2560 + (ni * 16 + l15) * 40 + quad * 8];
        acc_o[ni] = __builtin_amdgcn_mfma_f32_16x16x32_bf16(pa[ks], bv, acc_o[ni], 0, 0, 0);
      }
    }
  }

  // ---- epilogue: O / l, bf16 out ----
  #pragma unroll
  for (int ni = 0; ni < 4; ni++) {
    int col = hh * 64 + ni * 16 + l15;
    #pragma unroll
    for (int r = 0; r < 4; r++) {
      int row = rowBase + q0 + wm + quad * 4 + r;
      out[(size_t)row * DIM + col] = f2bf(acc_o[ni][r] / l_i[r]);
    }
  }
}

// =======================================================================
extern "C" void kernel_launch(void* const* d_in, const int* in_sizes, int n_in,
                              void* d_out, int out_size, void* d_ws, size_t ws_size,
                              hipStream_t stream) {
  const int*   ids  = (const int*)d_in[0];
  const float* tokE = (const float*)d_in[1];
  const float* posE = (const float*)d_in[2];
  const float* ln1g = (const float*)d_in[3];
  const float* ln1b = (const float*)d_in[4];
  const float* qkvw = (const float*)d_in[5];
  const float* qkvb = (const float*)d_in[6];
  const float* outw = (const float*)d_in[7];
  const float* outb = (const float*)d_in[8];
  const float* ln2g = (const float*)d_in[9];
  const float* ln2b = (const float*)d_in[10];
  const float* fc1w = (const float*)d_in[11];
  const float* fc1b = (const float*)d_in[12];
  const float* fc2w = (const float*)d_in[13];
  const float* fc2b = (const float*)d_in[14];
  const float* lnfg = (const float*)d_in[15];
  const float* lnfb = (const float*)d_in[16];
  float* logits = (float*)d_out;

  char* ws = (char*)d_ws;
  size_t off = 0;
  auto alloc = [&](size_t bytes) { void* p = ws + off; off += (bytes + 255) & ~(size_t)255; return p; };
  u16*   wt_qkv = (u16*)alloc((size_t)NL * 2304 * 768 * 2);
  u16*   wt_out = (u16*)alloc((size_t)NL * 768 * 768 * 2);
  u16*   wt_fc1 = (u16*)alloc((size_t)NL * 3072 * 768 * 2);
  u16*   wt_fc2 = (u16*)alloc((size_t)NL * 768 * 3072 * 2);
  u16*   tokEb  = (u16*)alloc((size_t)VOCAB * 768 * 2);
  float* x      = (float*)alloc((size_t)NTOK * 768 * 4);
  u16*   h      = (u16*)alloc((size_t)NTOK * 768 * 2);
  u16*   qkvbuf = (u16*)alloc((size_t)NTOK * 2304 * 2);
  u16*   attnb  = (u16*)alloc((size_t)NTOK * 768 * 2);
  u16*   ffh    = (u16*)alloc((size_t)NTOK * 3072 * 2);

  // ---- weight prep (every call: ws is re-poisoned) ----
  transpose_cast_kernel<<<dim3(36, 12, NL), 256, 0, stream>>>(qkvw, wt_qkv, 768, 2304);
  transpose_cast_kernel<<<dim3(12, 12, NL), 256, 0, stream>>>(outw, wt_out, 768, 768);
  transpose_cast_kernel<<<dim3(48, 12, NL), 256, 0, stream>>>(fc1w, wt_fc1, 768, 3072);
  transpose_cast_kernel<<<dim3(12, 48, NL), 256, 0, stream>>>(fc2w, wt_fc2, 3072, 768);
  long n4 = (long)VOCAB * 768 / 4;
  cast_bf16_kernel<<<(int)((n4 + 255) / 256), 256, 0, stream>>>(tokE, tokEb, n4);

  // ---- embedding ----
  embed_kernel<<<NTOK, 256, 0, stream>>>(ids, tokE, posE, x);

  // ---- transformer blocks ----
  for (int l = 0; l < NL; l++) {
    ln_kernel<<<NTOK, 256, 0, stream>>>(x, ln1g + l * 768, ln1b + l * 768, h);
    gemm_bt<1, 1><<<dim3(18, 32), 256, 0, stream>>>(h, wt_qkv + (size_t)l * 2304 * 768,
        qkvb + l * 2304, nullptr, nullptr, qkvbuf, NTOK, 2304, 768);
    attn_mfma_kernel<<<dim3(16, NB * NH), 256, 0, stream>>>(qkvbuf, attnb);
    gemm_bt<2, 0><<<dim3(6, 32), 256, 0, stream>>>(attnb, wt_out + (size_t)l * 768 * 768,
        outb + l * 768, x, x, nullptr, NTOK, 768, 768);
    ln_kernel<<<NTOK, 256, 0, stream>>>(x, ln2g + l * 768, ln2b + l * 768, h);
    gemm_bt<3, 1><<<dim3(24, 32), 256, 0, stream>>>(h, wt_fc1 + (size_t)l * 3072 * 768,
        fc1b + l * 3072, nullptr, nullptr, ffh, NTOK, 3072, 768);
    gemm_bt<2, 0><<<dim3(6, 32), 256, 0, stream>>>(ffh, wt_fc2 + (size_t)l * 768 * 3072,
        fc2b + l * 768, x, x, nullptr, NTOK, 768, 3072);
  }

  // ---- final LN + tied lm_head ----
  ln_kernel<<<NTOK, 256, 0, stream>>>(x, lnfg, lnfb, h);
  gemm_bt<0, 0><<<dim3((VOCAB + 127) / 128, 32), 256, 0, stream>>>(h, tokEb,
      nullptr, nullptr, logits, nullptr, NTOK, VOCAB, 768);
}

// Round 2
// 4375.414 us; speedup vs baseline: 4.0372x; 1.2164x over previous
//
#include <hip/hip_runtime.h>
#include <math.h>

#define NB 4
#define SEQ 1024
#define DIM 768
#define NH 12
#define HD 64
#define FF 3072
#define NL 12
#define VOCAB 50257
#define NTOK 4096   // NB*SEQ

typedef unsigned short u16;
typedef __attribute__((ext_vector_type(8))) short short8;   // 8 bf16 (guide-verified frag type)
typedef __attribute__((ext_vector_type(4))) float floatx4;

__device__ __forceinline__ u16 f2bf(float f) {
  union { float f; unsigned u; } v; v.f = f;
  unsigned u = v.u;
  u += 0x7fffu + ((u >> 16) & 1u);   // RNE
  return (u16)(u >> 16);
}

// async global->LDS, 16B per lane. LDS dest must be linear in lane order (wave-uniform base + lane*16).
__device__ __forceinline__ void gload16(const void* g, void* l) {
  __builtin_amdgcn_global_load_lds((const __attribute__((address_space(1))) unsigned int*)g,
                                   (__attribute__((address_space(3))) unsigned int*)l, 16, 0, 0);
}

// ---------------- embedding: x[row] = tok[id] + pos[s] ----------------
__global__ __launch_bounds__(256) void embed_kernel(const int* __restrict__ ids,
                                                    const float* __restrict__ tok,
                                                    const float* __restrict__ pos,
                                                    float* __restrict__ x) {
  int row = blockIdx.x;
  int s = row & (SEQ - 1);
  int id = ids[row];
  const float* te = tok + (size_t)id * DIM;
  const float* pe = pos + (size_t)s * DIM;
  float* xr = x + (size_t)row * DIM;
  for (int d = threadIdx.x; d < DIM; d += 256) xr[d] = te[d] + pe[d];
}

// ---------------- layernorm: fp32 in -> bf16 out ----------------
__global__ __launch_bounds__(256) void ln_kernel(const float* __restrict__ x,
                                                 const float* __restrict__ g,
                                                 const float* __restrict__ b,
                                                 u16* __restrict__ out) {
  int row = blockIdx.x;
  const float* xr = x + (size_t)row * DIM;
  int t = threadIdx.x;
  float v0 = xr[t], v1 = xr[t + 256], v2 = xr[t + 512];
  float s = v0 + v1 + v2;
  float s2 = v0*v0 + v1*v1 + v2*v2;
  #pragma unroll
  for (int off = 32; off; off >>= 1) { s += __shfl_xor(s, off); s2 += __shfl_xor(s2, off); }
  __shared__ float rs[4], rs2[4];
  int wave = t >> 6;
  if ((t & 63) == 0) { rs[wave] = s; rs2[wave] = s2; }
  __syncthreads();
  s = rs[0] + rs[1] + rs[2] + rs[3];
  s2 = rs2[0] + rs2[1] + rs2[2] + rs2[3];
  float mean = s * (1.f / DIM);
  float var = s2 * (1.f / DIM) - mean * mean;
  float rstd = rsqrtf(var + 1e-5f);
  u16* orow = out + (size_t)row * DIM;
  orow[t]       = f2bf(g[t]       * ((v0 - mean) * rstd) + b[t]);
  orow[t + 256] = f2bf(g[t + 256] * ((v1 - mean) * rstd) + b[t + 256]);
  orow[t + 512] = f2bf(g[t + 512] * ((v2 - mean) * rstd) + b[t + 512]);
}

// ---------------- weight prep: fp32 [K,N] -> bf16 [N,K], batched over layers ----------------
__global__ __launch_bounds__(256) void transpose_cast_kernel(const float* __restrict__ in,
                                                             u16* __restrict__ out, int K, int N) {
  __shared__ float tile[64][65];
  size_t off = (size_t)blockIdx.z * K * N;
  in += off; out += off;
  int k0 = blockIdx.y * 64, n0 = blockIdx.x * 64;
  int t = threadIdx.x;
  #pragma unroll
  for (int i = 0; i < 4; i++) {
    int idx = t + 256 * i;
    int r = idx >> 4, c = (idx & 15) * 4;
    float4 v = *(const float4*)&in[(size_t)(k0 + r) * N + n0 + c];
    tile[r][c] = v.x; tile[r][c+1] = v.y; tile[r][c+2] = v.z; tile[r][c+3] = v.w;
  }
  __syncthreads();
  #pragma unroll
  for (int i = 0; i < 4; i++) {
    int idx = t + 256 * i;
    int rn = idx >> 4, ck = (idx & 15) * 4;
    ushort4 o;
    o.x = f2bf(tile[ck+0][rn]); o.y = f2bf(tile[ck+1][rn]);
    o.z = f2bf(tile[ck+2][rn]); o.w = f2bf(tile[ck+3][rn]);
    *(ushort4*)&out[(size_t)(n0 + rn) * K + k0 + ck] = o;
  }
}

// ---------------- plain fp32 -> bf16 cast (tok_embed for lm_head) ----------------
__global__ __launch_bounds__(256) void cast_bf16_kernel(const float* __restrict__ in,
                                                        u16* __restrict__ out, long n4) {
  long i = (long)blockIdx.x * 256 + threadIdx.x;
  if (i >= n4) return;
  float4 v = ((const float4*)in)[i];
  ushort4 o; o.x = f2bf(v.x); o.y = f2bf(v.y); o.z = f2bf(v.z); o.w = f2bf(v.w);
  ((ushort4*)out)[i] = o;
}

// ---------------- GEMM: C[M,N] = A[M,K](bf16) * Bt[N,K](bf16)^T + epilogue ----------------
// m97 structure: 128x128 tile, BK=32, LINEAR LDS [128][32], global_load_lds width-16 staging.
// Grid: blockIdx.x = M-block (fast), blockIdx.y = N-block -> consecutive blocks share the B-panel.
// EPI: 0=none, 1=+bias, 2=+bias+resid, 3=+bias+gelu.  OUTBF: bf16 out if 1 else fp32.
template<int EPI, int OUTBF>
__global__ __launch_bounds__(256) void gemm_bt(const u16* __restrict__ A,
                                               const u16* __restrict__ Bt,
                                               const float* __restrict__ bias,
                                               const float* __restrict__ resid,
                                               float* __restrict__ outF,
                                               u16* __restrict__ outB,
                                               int M, int N, int K) {
  __shared__ u16 As[128 * 32];
  __shared__ u16 Bs[128 * 32];
  const int t = threadIdx.x;
  const int m0 = blockIdx.x * 128, n0 = blockIdx.y * 128;
  const int lane = t & 63, wave = t >> 6;
  const int wm = (wave >> 1) * 64, wn = (wave & 1) * 64;
  const int l15 = lane & 15, quad = lane >> 4;

  floatx4 acc[4][4];
  #pragma unroll
  for (int i = 0; i < 4; i++)
    #pragma unroll
    for (int j = 0; j < 4; j++) { floatx4 z = {0.f, 0.f, 0.f, 0.f}; acc[i][j] = z; }

  for (int k0 = 0; k0 < K; k0 += 32) {
    #pragma unroll
    for (int i = 0; i < 2; i++) {
      int idx = t + 256 * i;
      int row = idx >> 2, cc = (idx & 3) << 3;
      gload16(&A[(size_t)(m0 + row) * K + k0 + cc], &As[idx * 8]);
      int nr = n0 + row;
      if (nr < N) gload16(&Bt[(size_t)nr * K + k0 + cc], &Bs[idx * 8]);
      // OOB rows leave stale LDS; those acc columns are never stored.
    }
    __syncthreads();   // compiler drains vmcnt(0) before s_barrier -> gload_lds complete
    short8 af[4], bfr[4];
    #pragma unroll
    for (int mi = 0; mi < 4; mi++) af[mi] = *(const short8*)&As[(wm + mi * 16 + l15) * 32 + quad * 8];
    #pragma unroll
    for (int ni = 0; ni < 4; ni++) bfr[ni] = *(const short8*)&Bs[(wn + ni * 16 + l15) * 32 + quad * 8];
    #pragma unroll
    for (int mi = 0; mi < 4; mi++)
      #pragma unroll
      for (int ni = 0; ni < 4; ni++)
        acc[mi][ni] = __builtin_amdgcn_mfma_f32_16x16x32_bf16(af[mi], bfr[ni], acc[mi][ni], 0, 0, 0);
    __syncthreads();
  }

  #pragma unroll
  for (int mi = 0; mi < 4; mi++) {
    #pragma unroll
    for (int ni = 0; ni < 4; ni++) {
      int gc = n0 + wn + ni * 16 + l15;
      if (gc >= N) continue;
      #pragma unroll
      for (int r = 0; r < 4; r++) {
        int gr = m0 + wm + mi * 16 + quad * 4 + r;
        float v = acc[mi][ni][r];
        if (EPI >= 1) v += bias[gc];
        if (EPI == 2) v += resid[(size_t)gr * N + gc];
        if (EPI == 3) {
          float u = 0.7978845608028654f * (v + 0.044715f * v * v * v);
          v = 0.5f * v * (1.f + tanhf(u));
        }
        size_t o = (size_t)gr * N + gc;
        if (OUTBF) outB[o] = f2bf(v); else outF[o] = v;
      }
    }
  }
}

// ---------------- MFMA flash attention: qkv bf16 [NTOK, 3*DIM] -> out bf16 [NTOK, DIM] ----------
// Block: one (b,h), 64 q-rows. 4 waves, wave w owns q-rows [w*16, w*16+16).
// LDS tiles use the GEMM-proven two-slab layout: offset = (col>>5)*2560 + row*40 + (col&31).
// QPs holds Q during init (frags hoisted to regs), then is reused as the P tile.
__global__ __launch_bounds__(256) void attn_mfma_kernel(const u16* __restrict__ qkv,
                                                        u16* __restrict__ out) {
  __shared__ u16 QPs[5120];
  __shared__ u16 Ks[5120];
  __shared__ u16 Vt[5120];
  const int qb = 15 - blockIdx.x;       // longest-first for causal imbalance
  const int bh = blockIdx.y;            // b*NH + h
  const int bb = bh / NH, hh = bh % NH;
  const int rowBase = bb * SEQ;
  const int q0 = qb * 64;
  const int t = threadIdx.x, lane = t & 63, wave = t >> 6;
  const int l15 = lane & 15, quad = lane >> 4;
  const int wm = wave * 16;             // wave's first q-row within tile

  // ---- stage Q tile (bf16 passthrough), hoist A-frags to registers ----
  #pragma unroll
  for (int i = 0; i < 2; i++) {
    int idx = t + 256 * i;
    int r = idx >> 3, c8 = (idx & 7) * 8;
    *(uint4*)&QPs[(c8 >> 5) * 2560 + r * 40 + (c8 & 31)] =
        *(const uint4*)&qkv[(size_t)(rowBase + q0 + r) * 2304 + hh * 64 + c8];
  }
  __syncthreads();
  short8 af_q[2];
  af_q[0] = *(const short8*)&QPs[(wm + l15) * 40 + quad * 8];
  af_q[1] = *(const short8*)&QPs[2560 + (wm + l15) * 40 + quad * 8];

  floatx4 acc_o[4];
  float m_i[4], l_i[4];
  #pragma unroll
  for (int ni = 0; ni < 4; ni++) { floatx4 z = {0.f, 0.f, 0.f, 0.f}; acc_o[ni] = z; }
  #pragma unroll
  for (int r = 0; r < 4; r++) { m_i[r] = -1e30f; l_i[r] = 0.f; }

  for (int kt = 0; kt <= qb; kt++) {
    __syncthreads();                    // protect Ks/Vt from previous iteration's readers
    // ---- stage K tile ----
    #pragma unroll
    for (int i = 0; i < 2; i++) {
      int idx = t + 256 * i;
      int r = idx >> 3, c8 = (idx & 7) * 8;
      *(uint4*)&Ks[(c8 >> 5) * 2560 + r * 40 + (c8 & 31)] =
          *(const uint4*)&qkv[(size_t)(rowBase + kt * 64 + r) * 2304 + 768 + hh * 64 + c8];
    }
    // ---- stage V tile transposed: Vt[d][kv] = V[kv][d] ----
    #pragma unroll
    for (int i = 0; i < 4; i++) {
      int idx = t + 256 * i;
      int d = idx & 63, kv0 = (idx >> 6) * 4;
      const u16* src = &qkv[(size_t)(rowBase + kt * 64 + kv0) * 2304 + 1536 + hh * 64 + d];
      ushort4 o;
      o.x = src[0]; o.y = src[2304]; o.z = src[2 * 2304]; o.w = src[3 * 2304];
      *(ushort4*)&Vt[(kv0 >> 5) * 2560 + d * 40 + (kv0 & 31)] = o;
    }
    __syncthreads();

    // ---- scores: acc_s[ni] = Q(16 x 64) . K^T, C layout row=quad*4+r col=ni*16+l15 ----
    floatx4 acc_s[4];
    #pragma unroll
    for (int ni = 0; ni < 4; ni++) {
      floatx4 z = {0.f, 0.f, 0.f, 0.f}; acc_s[ni] = z;
      #pragma unroll
      for (int ks = 0; ks < 2; ks++) {
        short8 bk = *(const short8*)&Ks[ks * 2560 + (ni * 16 + l15) * 40 + quad * 8];
        acc_s[ni] = __builtin_amdgcn_mfma_f32_16x16x32_bf16(af_q[ks], bk, acc_s[ni], 0, 0, 0);
      }
    }

    // ---- online softmax (rows are quad-private: 4-step butterfly over 16 lanes) ----
    const bool diag = (kt == qb);
    #pragma unroll
    for (int r = 0; r < 4; r++) {
      float mx = -1e30f;
      #pragma unroll
      for (int ni = 0; ni < 4; ni++) {
        float s = acc_s[ni][r] * 0.125f;
        if (diag && (ni * 16 + l15) > (wm + quad * 4 + r)) s = -1e30f;
        acc_s[ni][r] = s;
        mx = fmaxf(mx, s);
      }
      #pragma unroll
      for (int off = 8; off; off >>= 1) mx = fmaxf(mx, __shfl_xor(mx, off));
      float mnew = fmaxf(m_i[r], mx);
      float alpha = __expf(m_i[r] - mnew);
      m_i[r] = mnew;
      float rs = 0.f;
      #pragma unroll
      for (int ni = 0; ni < 4; ni++) {
        float pv = __expf(acc_s[ni][r] - mnew);
        acc_s[ni][r] = pv;
        rs += pv;
      }
      #pragma unroll
      for (int off = 8; off; off >>= 1) rs += __shfl_xor(rs, off);
      l_i[r] = l_i[r] * alpha + rs;
      #pragma unroll
      for (int ni = 0; ni < 4; ni++) acc_o[ni][r] *= alpha;
      // write P row to LDS (wave-private rows wm..wm+15)
      int row = wm + quad * 4 + r;
      #pragma unroll
      for (int ni = 0; ni < 4; ni++) {
        int col = ni * 16 + l15;
        QPs[(col >> 5) * 2560 + row * 40 + (col & 31)] = f2bf(acc_s[ni][r]);
      }
    }
    asm volatile("s_waitcnt lgkmcnt(0)" ::: "memory");  // wave-private P write->read fence

    // ---- O += P(16 x 64) . V : A-frags from QPs, B-frags from Vt ----
    short8 pa[2];
    pa[0] = *(const short8*)&QPs[(wm + l15) * 40 + quad * 8];
    pa[1] = *(const short8*)&QPs[2560 + (wm + l15) * 40 + quad * 8];
    #pragma unroll
    for (int ni = 0; ni < 4; ni++) {
      #pragma unroll
      for (int ks = 0; ks < 2; ks++) {
        short8 bv = *(const short8*)&Vt[ks * 2560 + (ni * 16 + l15) * 40 + quad * 8];
        acc_o[ni] = __builtin_amdgcn_mfma_f32_16x16x32_bf16(pa[ks], bv, acc_o[ni], 0, 0, 0);
      }
    }
  }

  // ---- epilogue: O / l, bf16 out ----
  #pragma unroll
  for (int ni = 0; ni < 4; ni++) {
    int col = hh * 64 + ni * 16 + l15;
    #pragma unroll
    for (int r = 0; r < 4; r++) {
      int row = rowBase + q0 + wm + quad * 4 + r;
      out[(size_t)row * DIM + col] = f2bf(acc_o[ni][r] / l_i[r]);
    }
  }
}

// =======================================================================
extern "C" void kernel_launch(void* const* d_in, const int* in_sizes, int n_in,
                              void* d_out, int out_size, void* d_ws, size_t ws_size,
                              hipStream_t stream) {
  const int*   ids  = (const int*)d_in[0];
  const float* tokE = (const float*)d_in[1];
  const float* posE = (const float*)d_in[2];
  const float* ln1g = (const float*)d_in[3];
  const float* ln1b = (const float*)d_in[4];
  const float* qkvw = (const float*)d_in[5];
  const float* qkvb = (const float*)d_in[6];
  const float* outw = (const float*)d_in[7];
  const float* outb = (const float*)d_in[8];
  const float* ln2g = (const float*)d_in[9];
  const float* ln2b = (const float*)d_in[10];
  const float* fc1w = (const float*)d_in[11];
  const float* fc1b = (const float*)d_in[12];
  const float* fc2w = (const float*)d_in[13];
  const float* fc2b = (const float*)d_in[14];
  const float* lnfg = (const float*)d_in[15];
  const float* lnfb = (const float*)d_in[16];
  float* logits = (float*)d_out;

  char* ws = (char*)d_ws;
  size_t off = 0;
  auto alloc = [&](size_t bytes) { void* p = ws + off; off += (bytes + 255) & ~(size_t)255; return p; };
  u16*   wt_qkv = (u16*)alloc((size_t)NL * 2304 * 768 * 2);
  u16*   wt_out = (u16*)alloc((size_t)NL * 768 * 768 * 2);
  u16*   wt_fc1 = (u16*)alloc((size_t)NL * 3072 * 768 * 2);
  u16*   wt_fc2 = (u16*)alloc((size_t)NL * 768 * 3072 * 2);
  u16*   tokEb  = (u16*)alloc((size_t)VOCAB * 768 * 2);
  float* x      = (float*)alloc((size_t)NTOK * 768 * 4);
  u16*   h      = (u16*)alloc((size_t)NTOK * 768 * 2);
  u16*   qkvbuf = (u16*)alloc((size_t)NTOK * 2304 * 2);
  u16*   attnb  = (u16*)alloc((size_t)NTOK * 768 * 2);
  u16*   ffh    = (u16*)alloc((size_t)NTOK * 3072 * 2);

  // ---- weight prep (every call: ws is re-poisoned) ----
  transpose_cast_kernel<<<dim3(36, 12, NL), 256, 0, stream>>>(qkvw, wt_qkv, 768, 2304);
  transpose_cast_kernel<<<dim3(12, 12, NL), 256, 0, stream>>>(outw, wt_out, 768, 768);
  transpose_cast_kernel<<<dim3(48, 12, NL), 256, 0, stream>>>(fc1w, wt_fc1, 768, 3072);
  transpose_cast_kernel<<<dim3(12, 48, NL), 256, 0, stream>>>(fc2w, wt_fc2, 3072, 768);
  long n4 = (long)VOCAB * 768 / 4;
  cast_bf16_kernel<<<(int)((n4 + 255) / 256), 256, 0, stream>>>(tokE, tokEb, n4);

  // ---- embedding ----
  embed_kernel<<<NTOK, 256, 0, stream>>>(ids, tokE, posE, x);

  // ---- transformer blocks ----
  for (int l = 0; l < NL; l++) {
    ln_kernel<<<NTOK, 256, 0, stream>>>(x, ln1g + l * 768, ln1b + l * 768, h);
    gemm_bt<1, 1><<<dim3(32, 18), 256, 0, stream>>>(h, wt_qkv + (size_t)l * 2304 * 768,
        qkvb + l * 2304, nullptr, nullptr, qkvbuf, NTOK, 2304, 768);
    attn_mfma_kernel<<<dim3(16, NB * NH), 256, 0, stream>>>(qkvbuf, attnb);
    gemm_bt<2, 0><<<dim3(32, 6), 256, 0, stream>>>(attnb, wt_out + (size_t)l * 768 * 768,
        outb + l * 768, x, x, nullptr, NTOK, 768, 768);
    ln_kernel<<<NTOK, 256, 0, stream>>>(x, ln2g + l * 768, ln2b + l * 768, h);
    gemm_bt<3, 1><<<dim3(32, 24), 256, 0, stream>>>(h, wt_fc1 + (size_t)l * 3072 * 768,
        fc1b + l * 3072, nullptr, nullptr, ffh, NTOK, 3072, 768);
    gemm_bt<2, 0><<<dim3(32, 6), 256, 0, stream>>>(ffh, wt_fc2 + (size_t)l * 768 * 3072,
        fc2b + l * 768, x, x, nullptr, NTOK, 768, 3072);
  }

  // ---- final LN + tied lm_head ----
  ln_kernel<<<NTOK, 256, 0, stream>>>(x, lnfg, lnfb, h);
  gemm_bt<0, 0><<<dim3(32, (VOCAB + 127) / 128), 256, 0, stream>>>(h, tokEb,
      nullptr, nullptr, logits, nullptr, NTOK, VOCAB, 768);
}